// Round 2
// baseline (377.955 us; speedup 1.0000x reference)
//
#include <hip/hip_runtime.h>

constexpr int NG = 2048;   // gaussians
constexpr int DF = 64;     // feature dim
constexpr int IW = 128;
constexpr int IH = 128;
constexpr int SEG = 8;           // z-segments (waves per block)
constexpr int SEGN = NG / SEG;   // 256 gaussians per segment
constexpr int RB = SEG * 64;     // 512 threads per render block

#define P_NEAR 0.01f
#define P_BLUR 0.3f
#define P_AMIN (1.0f/255.0f)
#define P_AMAX 0.999f

// render LDS layout (floats). lists + T + acc, no overlap, 145 KB total.
constexpr int L_LIST = 0;                       // SEG*SEGN ints = 2048
constexpr int L_T    = SEG * SEGN;              // 2048 .. +512
constexpr int L_ACC  = L_T + SEG * 64;          // 2560
constexpr int ACC_STRIDE = 66;                  // 64 + 2 pad (bank spread, 8B aligned)
constexpr int L_TOTAL = L_ACC + SEG * 64 * ACC_STRIDE;  // 36352 floats = 145408 B

// ---------------------------------------------------------------------------
__device__ inline void invert4x4(const float* m, float* inv) {
    inv[0]  =  m[5]*m[10]*m[15] - m[5]*m[11]*m[14] - m[9]*m[6]*m[15] + m[9]*m[7]*m[14] + m[13]*m[6]*m[11] - m[13]*m[7]*m[10];
    inv[4]  = -m[4]*m[10]*m[15] + m[4]*m[11]*m[14] + m[8]*m[6]*m[15] - m[8]*m[7]*m[14] - m[12]*m[6]*m[11] + m[12]*m[7]*m[10];
    inv[8]  =  m[4]*m[9]*m[15]  - m[4]*m[11]*m[13] - m[8]*m[5]*m[15] + m[8]*m[7]*m[13] + m[12]*m[5]*m[11] - m[12]*m[7]*m[9];
    inv[12] = -m[4]*m[9]*m[14]  + m[4]*m[10]*m[13] + m[8]*m[5]*m[14] - m[8]*m[6]*m[13] - m[12]*m[5]*m[10] + m[12]*m[6]*m[9];
    inv[1]  = -m[1]*m[10]*m[15] + m[1]*m[11]*m[14] + m[9]*m[2]*m[15] - m[9]*m[3]*m[14] - m[13]*m[2]*m[11] + m[13]*m[3]*m[10];
    inv[5]  =  m[0]*m[10]*m[15] - m[0]*m[11]*m[14] - m[8]*m[2]*m[15] + m[8]*m[3]*m[14] + m[12]*m[2]*m[11] - m[12]*m[3]*m[10];
    inv[9]  = -m[0]*m[9]*m[15]  + m[0]*m[11]*m[13] + m[8]*m[1]*m[15] - m[8]*m[3]*m[13] - m[12]*m[1]*m[11] + m[12]*m[3]*m[9];
    inv[13] =  m[0]*m[9]*m[14]  - m[0]*m[10]*m[13] - m[8]*m[1]*m[14] + m[8]*m[2]*m[13] + m[12]*m[1]*m[10] - m[12]*m[2]*m[9];
    inv[2]  =  m[1]*m[6]*m[15]  - m[1]*m[7]*m[14]  - m[5]*m[2]*m[15] + m[5]*m[3]*m[14] + m[13]*m[2]*m[7]  - m[13]*m[3]*m[6];
    inv[6]  = -m[0]*m[6]*m[15]  + m[0]*m[7]*m[14]  + m[4]*m[2]*m[15] - m[4]*m[3]*m[14] - m[12]*m[2]*m[7]  + m[12]*m[3]*m[6];
    inv[10] =  m[0]*m[5]*m[15]  - m[0]*m[7]*m[13]  - m[4]*m[1]*m[15] + m[4]*m[3]*m[13] + m[12]*m[1]*m[7]  - m[12]*m[3]*m[5];
    inv[14] = -m[0]*m[5]*m[14]  + m[0]*m[6]*m[13]  + m[4]*m[1]*m[14] - m[4]*m[2]*m[13] - m[12]*m[1]*m[6]  + m[12]*m[2]*m[5];
    inv[3]  = -m[1]*m[6]*m[11]  + m[1]*m[7]*m[10]  + m[5]*m[2]*m[11] - m[5]*m[3]*m[10] - m[9]*m[2]*m[7]   + m[9]*m[3]*m[6];
    inv[7]  =  m[0]*m[6]*m[11]  - m[0]*m[7]*m[10]  - m[4]*m[2]*m[11] + m[4]*m[3]*m[10] + m[8]*m[2]*m[7]   - m[8]*m[3]*m[6];
    inv[11] = -m[0]*m[5]*m[11]  + m[0]*m[7]*m[9]   + m[4]*m[1]*m[11] - m[4]*m[3]*m[9]  - m[8]*m[1]*m[7]   + m[8]*m[3]*m[5];
    inv[15] =  m[0]*m[5]*m[10]  - m[0]*m[6]*m[9]   - m[4]*m[1]*m[10] + m[4]*m[2]*m[9]  + m[8]*m[1]*m[6]   - m[8]*m[2]*m[5];
    float det = m[0]*inv[0] + m[1]*inv[4] + m[2]*inv[8] + m[3]*inv[12];
    det = 1.0f / det;
    #pragma unroll
    for (int i = 0; i < 16; ++i) inv[i] *= det;
}

// ---------------------------------------------------------------------------
// Kernel 1: fused preprocess + bitonic argsort (single block, 1024 threads).
// Writes per-gaussian eval params (8 f, AoS), cull bbox (4 f), and sorted
// index list sidx (stable (z, idx) key, matches jnp.argsort).
__global__ __launch_bounds__(1024) void prep_sort_kernel(
    const float* __restrict__ means,  const float* __restrict__ quats,
    const float* __restrict__ scales, const float* __restrict__ opac_logits,
    const float* __restrict__ c2o,    const float* __restrict__ Kmat,
    float* __restrict__ evalp, float* __restrict__ bboxp, int* __restrict__ sidx)
{
    __shared__ float kz[NG];
    __shared__ int   kv[NG];
    const int tid = threadIdx.x;

    float inv[16];
    {
        float m[16];
        #pragma unroll
        for (int t = 0; t < 16; ++t) m[t] = c2o[t];
        invert4x4(m, inv);   // viewmat, row-major
    }
    const float fx = Kmat[0], fy = Kmat[4], cx = Kmat[2], cy = Kmat[5];

    for (int i = tid; i < NG; i += 1024) {
        float mx = means[i*3+0], my = means[i*3+1], mz = means[i*3+2];
        float X = inv[0]*mx + inv[1]*my + inv[2]*mz  + inv[3];
        float Y = inv[4]*mx + inv[5]*my + inv[6]*mz  + inv[7];
        float Z = inv[8]*mx + inv[9]*my + inv[10]*mz + inv[11];

        float qw = quats[i*4+0], qx = quats[i*4+1], qy = quats[i*4+2], qz = quats[i*4+3];
        float qn = rsqrtf(qw*qw + qx*qx + qy*qy + qz*qz);
        qw *= qn; qx *= qn; qy *= qn; qz *= qn;
        float R00 = 1.f - 2.f*(qy*qy + qz*qz), R01 = 2.f*(qx*qy - qw*qz), R02 = 2.f*(qx*qz + qw*qy);
        float R10 = 2.f*(qx*qy + qw*qz), R11 = 1.f - 2.f*(qx*qx + qz*qz), R12 = 2.f*(qy*qz - qw*qx);
        float R20 = 2.f*(qx*qz - qw*qy), R21 = 2.f*(qy*qz + qw*qx), R22 = 1.f - 2.f*(qx*qx + qy*qy);

        float s0 = expf(scales[i*3+0]), s1 = expf(scales[i*3+1]), s2 = expf(scales[i*3+2]);
        float M00 = R00*s0, M01 = R01*s1, M02 = R02*s2;
        float M10 = R10*s0, M11 = R11*s1, M12 = R12*s2;
        float M20 = R20*s0, M21 = R21*s1, M22 = R22*s2;

        float V[3][3];
        V[0][0] = M00*M00 + M01*M01 + M02*M02;
        V[0][1] = M00*M10 + M01*M11 + M02*M12;
        V[0][2] = M00*M20 + M01*M21 + M02*M22;
        V[1][1] = M10*M10 + M11*M11 + M12*M12;
        V[1][2] = M10*M20 + M11*M21 + M12*M22;
        V[2][2] = M20*M20 + M21*M21 + M22*M22;
        V[1][0] = V[0][1]; V[2][0] = V[0][2]; V[2][1] = V[1][2];

        float Rv[3][3] = {{inv[0],inv[1],inv[2]},{inv[4],inv[5],inv[6]},{inv[8],inv[9],inv[10]}};
        float Tm[3][3], C[3][3];
        #pragma unroll
        for (int r = 0; r < 3; ++r)
            #pragma unroll
            for (int c = 0; c < 3; ++c)
                Tm[r][c] = Rv[r][0]*V[0][c] + Rv[r][1]*V[1][c] + Rv[r][2]*V[2][c];
        #pragma unroll
        for (int r = 0; r < 3; ++r)
            #pragma unroll
            for (int c = 0; c < 3; ++c)
                C[r][c] = Tm[r][0]*Rv[c][0] + Tm[r][1]*Rv[c][1] + Tm[r][2]*Rv[c][2];

        float rz = 1.0f / Z;
        float j00 = fx*rz, j02 = -fx*X*rz*rz;
        float j11 = fy*rz, j12 = -fy*Y*rz*rz;

        float c00 = j00*j00*C[0][0] + 2.f*j00*j02*C[0][2] + j02*j02*C[2][2];
        float c01 = j00*j11*C[0][1] + j00*j12*C[0][2] + j02*j11*C[1][2] + j02*j12*C[2][2];
        float c11 = j11*j11*C[1][1] + 2.f*j11*j12*C[1][2] + j12*j12*C[2][2];

        float a = c00 + P_BLUR;
        float b = c01;
        float c = c11 + P_BLUR;
        float det = a*c - b*b;

        float pmx = fx*X*rz + cx;
        float pmy = fy*Y*rz + cy;

        float lam = 0.5f*(a + c) + sqrtf(fmaxf(0.25f*(a - c)*(a - c) + b*b, 1e-12f));
        float radius = 3.0f * sqrtf(lam);
        bool valid = (Z > P_NEAR) && (det > 0.0f) && (radius > 3.0f);

        float op = 1.0f / (1.0f + expf(-opac_logits[i]));

        float cA = 0.f, cB = 0.f, cC = 0.f, rx = -1e9f, ry = -1e9f;
        if (valid) {
            float rdet = 1.0f / det;
            cA = c * rdet; cB = -b * rdet; cC = a * rdet;
            // exact conservative extent: alpha >= A_MIN requires sigma <= ln(255*op),
            // and min-over-dy sigma = dx^2/(2a)  =>  |dx| <= sqrt(2*a*smax).
            float smax = logf(255.0f * op);
            if (smax > 0.f) {
                rx = sqrtf(2.f * a * smax);
                ry = sqrtf(2.f * c * smax);
            }
        } else {
            op = 0.f;
        }

        evalp[i*8+0] = pmx; evalp[i*8+1] = pmy;
        evalp[i*8+2] = cA;  evalp[i*8+3] = cB;
        evalp[i*8+4] = cC;  evalp[i*8+5] = op;
        evalp[i*8+6] = 0.f; evalp[i*8+7] = 0.f;
        bboxp[i*4+0] = pmx; bboxp[i*4+1] = pmy;
        bboxp[i*4+2] = rx;  bboxp[i*4+3] = ry;

        kz[i] = Z;
        kv[i] = i;
    }
    __syncthreads();

    // bitonic sort, stable via (z, idx)
    for (int kk = 2; kk <= NG; kk <<= 1) {
        for (int j = kk >> 1; j > 0; j >>= 1) {
            for (int t = tid; t < NG; t += 1024) {
                int ixj = t ^ j;
                if (ixj > t) {
                    bool up_dir = ((t & kk) == 0);
                    float ka = kz[t], kb = kz[ixj];
                    int   va = kv[t], vb = kv[ixj];
                    bool a_gt_b = (ka > kb) || (ka == kb && va > vb);
                    if (up_dir ? a_gt_b : !a_gt_b) {
                        kz[t] = kb; kz[ixj] = ka; kv[t] = vb; kv[ixj] = va;
                    }
                }
            }
            __syncthreads();
        }
    }
    for (int i = tid; i < NG; i += 1024) sidx[i] = kv[i];
}

// ---------------------------------------------------------------------------
// Kernel 2: render. One block per 8x8 pixel tile (256 blocks, 1 per CU).
// 8 waves per block; wave s owns z-segment s. lane = pixel, serial
// front-to-back compositing in registers (no cross-lane ops). Per-segment
// (acc[64], T) combined affinely through LDS:
//   out = a0 + T0*(a1 + T1*(a2 + ... ))
#define STEP(E0, E1, CBUF)                                                    \
    {                                                                         \
        float dx = px - (E0).x, dy = py - (E0).y;                             \
        float sig = 0.5f*((E0).z*dx*dx + (E1).x*dy*dy) + (E0).w*dx*dy;        \
        float al = fminf((E1).y * __expf(-sig), P_AMAX);                      \
        al = (sig >= 0.f && al >= P_AMIN) ? al : 0.f;                         \
        float wv = T * al; T *= (1.f - al);                                   \
        _Pragma("unroll")                                                     \
        for (int q = 0; q < 16; ++q) {                                        \
            acc[4*q+0] = fmaf(wv, CBUF[q].x, acc[4*q+0]);                     \
            acc[4*q+1] = fmaf(wv, CBUF[q].y, acc[4*q+1]);                     \
            acc[4*q+2] = fmaf(wv, CBUF[q].z, acc[4*q+2]);                     \
            acc[4*q+3] = fmaf(wv, CBUF[q].w, acc[4*q+3]);                     \
        }                                                                     \
    }

__global__ __launch_bounds__(RB, 2) void render_kernel(
    const float* __restrict__ evalp, const float* __restrict__ bboxp,
    const int* __restrict__ sidx,    const float* __restrict__ colors,
    float* __restrict__ out)
{
    extern __shared__ float lds[];
    const int tid  = threadIdx.x;
    const int lane = tid & 63;
    const int seg  = tid >> 6;
    const int tile = blockIdx.x;
    const int tx = (tile & 15) * 8;
    const int ty = (tile >> 4) * 8;
    const float px = tx + (lane & 7) + 0.5f;
    const float py = ty + (lane >> 3) + 0.5f;
    const float cxt = tx + 4.0f, cyt = ty + 4.0f;   // tile center

    // ---- cull: compact this segment's overlapping gaussians (z order kept)
    int* list = (int*)(lds + L_LIST) + seg * SEGN;
    int cnt = 0;
    const float4* bb4 = (const float4*)bboxp;
    for (int c = 0; c < SEGN; c += 64) {
        int g  = seg * SEGN + c + lane;      // sorted position
        int oi = sidx[g];
        float4 bb = bb4[oi];
        bool sel = (fabsf(bb.x - cxt) <= bb.z + 3.5f) &&
                   (fabsf(bb.y - cyt) <= bb.w + 3.5f);
        unsigned long long m = __ballot(sel);
        if (sel) list[cnt + (int)__popcll(m & ((1ull << lane) - 1ull))] = oi;
        cnt += (int)__popcll(m);
    }

    float acc[64];
    #pragma unroll
    for (int f = 0; f < 64; ++f) acc[f] = 0.f;
    float T = 1.0f;

    const float4* ep4 = (const float4*)evalp;
    const float4* cp4 = (const float4*)colors;

    if (cnt > 0) {
        float4 cA[16], cB[16];
        int ia = list[0];
        int ib = (cnt > 1) ? list[1] : ia;
        float4 a0 = ep4[ia*2], a1 = ep4[ia*2+1];
        float4 b0 = ep4[ib*2], b1 = ep4[ib*2+1];
        #pragma unroll
        for (int q = 0; q < 16; ++q) cA[q] = cp4[ia*16 + q];
        #pragma unroll
        for (int q = 0; q < 16; ++q) cB[q] = cp4[ib*16 + q];

        int i = 0;
        for (; i + 2 <= cnt; i += 2) {
            int i2 = (i + 2 < cnt) ? list[i + 2] : ia;
            int i3 = (i + 3 < cnt) ? list[i + 3] : ia;
            float4 n0 = ep4[i2*2], n1 = ep4[i2*2+1];
            float4 m0 = ep4[i3*2], m1 = ep4[i3*2+1];
            STEP(a0, a1, cA);
            #pragma unroll
            for (int q = 0; q < 16; ++q) cA[q] = cp4[i2*16 + q];   // colors i+2
            STEP(b0, b1, cB);
            #pragma unroll
            for (int q = 0; q < 16; ++q) cB[q] = cp4[i3*16 + q];   // colors i+3
            a0 = n0; a1 = n1; b0 = m0; b1 = m1;
        }
        if (i < cnt) STEP(a0, a1, cA);
    }

    // ---- stage per-segment (acc, T) to LDS
    {
        float* ab = lds + L_ACC + (size_t)(seg * 64 + lane) * ACC_STRIDE;
        #pragma unroll
        for (int q = 0; q < 32; ++q)
            *(float2*)(ab + 2*q) = make_float2(acc[2*q], acc[2*q+1]);
        lds[L_T + seg*64 + lane] = T;
    }
    __syncthreads();

    // ---- combine segments + write out. thread -> (pixel p, 8 features)
    {
        int p  = tid >> 3;
        int f0 = (tid & 7) * 8;
        float r[8];
        const float* ab = lds + L_ACC + (size_t)((SEG-1)*64 + p) * ACC_STRIDE + f0;
        #pragma unroll
        for (int j = 0; j < 4; ++j) {
            float2 u = *(const float2*)(ab + 2*j);
            r[2*j] = u.x; r[2*j+1] = u.y;
        }
        #pragma unroll
        for (int s = SEG - 2; s >= 0; --s) {
            float Ts = lds[L_T + s*64 + p];
            const float* as_ = lds + L_ACC + (size_t)(s*64 + p) * ACC_STRIDE + f0;
            #pragma unroll
            for (int j = 0; j < 4; ++j) {
                float2 u = *(const float2*)(as_ + 2*j);
                r[2*j]   = fmaf(Ts, r[2*j],   u.x);
                r[2*j+1] = fmaf(Ts, r[2*j+1], u.y);
            }
        }
        int pyg = ty + (p >> 3), pxg = tx + (p & 7);
        float* op_ = out + (size_t)(pyg * IW + pxg) * DF + f0;
        *(float4*)op_       = make_float4(r[0], r[1], r[2], r[3]);
        *(float4*)(op_ + 4) = make_float4(r[4], r[5], r[6], r[7]);
    }
}

// ---------------------------------------------------------------------------
extern "C" void kernel_launch(void* const* d_in, const int* in_sizes, int n_in,
                              void* d_out, int out_size, void* d_ws, size_t ws_size,
                              hipStream_t stream) {
    const float* means  = (const float*)d_in[0];
    const float* quats  = (const float*)d_in[1];
    const float* scales = (const float*)d_in[2];
    const float* opac   = (const float*)d_in[3];
    const float* colors = (const float*)d_in[4];
    const float* c2o    = (const float*)d_in[5];
    const float* Kmat   = (const float*)d_in[6];
    float* out = (float*)d_out;

    // ws (floats): evalp[NG*8] | bboxp[NG*4] | sidx[NG]  = 104 KiB
    float* ws    = (float*)d_ws;
    float* evalp = ws;
    float* bboxp = ws + NG*8;
    int*   sidx  = (int*)(ws + NG*12);

    // allow >64KB dynamic LDS (no-op if unnecessary on this ROCm)
    (void)hipFuncSetAttribute((const void*)render_kernel,
                              hipFuncAttributeMaxDynamicSharedMemorySize,
                              L_TOTAL * 4);

    prep_sort_kernel<<<1, 1024, 0, stream>>>(means, quats, scales, opac, c2o, Kmat,
                                             evalp, bboxp, sidx);
    render_kernel<<<IH*IW/64, RB, L_TOTAL*4, stream>>>(evalp, bboxp, sidx, colors, out);
}

// Round 3
// 128.168 us; speedup vs baseline: 2.9489x; 2.9489x over previous
//
#include <hip/hip_runtime.h>

constexpr int NG = 2048;   // gaussians
constexpr int DF = 64;     // feature dim
constexpr int IW = 128;
constexpr int IH = 128;
constexpr int SEG = 8;           // z-segments (waves per render block)
constexpr int SEGN = NG / SEG;   // 256 gaussians per segment
constexpr int RB = SEG * 64;     // 512 threads per render block
constexpr int NB = 1024;         // sort buckets

#define P_NEAR 0.01f
#define P_BLUR 0.3f
#define P_AMIN (1.0f/255.0f)
#define P_AMAX 0.999f

// render dynamic-LDS layout (floats)
constexpr int L_LIST = 0;                       // SEG*SEGN ints = 2048
constexpr int L_T    = SEG * SEGN;              // 2048
constexpr int L_ACC  = L_T + SEG * 64;          // 2560
constexpr int ACC_STRIDE = 66;                  // 64 + 2 pad
constexpr int L_TOTAL = L_ACC + SEG * 64 * ACC_STRIDE;  // 36352 floats = 145408 B

// ---------------------------------------------------------------------------
__device__ inline void invert4x4(const float* m, float* inv) {
    inv[0]  =  m[5]*m[10]*m[15] - m[5]*m[11]*m[14] - m[9]*m[6]*m[15] + m[9]*m[7]*m[14] + m[13]*m[6]*m[11] - m[13]*m[7]*m[10];
    inv[4]  = -m[4]*m[10]*m[15] + m[4]*m[11]*m[14] + m[8]*m[6]*m[15] - m[8]*m[7]*m[14] - m[12]*m[6]*m[11] + m[12]*m[7]*m[10];
    inv[8]  =  m[4]*m[9]*m[15]  - m[4]*m[11]*m[13] - m[8]*m[5]*m[15] + m[8]*m[7]*m[13] + m[12]*m[5]*m[11] - m[12]*m[7]*m[9];
    inv[12] = -m[4]*m[9]*m[14]  + m[4]*m[10]*m[13] + m[8]*m[5]*m[14] - m[8]*m[6]*m[13] - m[12]*m[5]*m[10] + m[12]*m[6]*m[9];
    inv[1]  = -m[1]*m[10]*m[15] + m[1]*m[11]*m[14] + m[9]*m[2]*m[15] - m[9]*m[3]*m[14] - m[13]*m[2]*m[11] + m[13]*m[3]*m[10];
    inv[5]  =  m[0]*m[10]*m[15] - m[0]*m[11]*m[14] - m[8]*m[2]*m[15] + m[8]*m[3]*m[14] + m[12]*m[2]*m[11] - m[12]*m[3]*m[10];
    inv[9]  = -m[0]*m[9]*m[15]  + m[0]*m[11]*m[13] + m[8]*m[1]*m[15] - m[8]*m[3]*m[13] - m[12]*m[1]*m[11] + m[12]*m[3]*m[9];
    inv[13] =  m[0]*m[9]*m[14]  - m[0]*m[10]*m[13] - m[8]*m[1]*m[14] + m[8]*m[2]*m[13] + m[12]*m[1]*m[10] - m[12]*m[2]*m[9];
    inv[2]  =  m[1]*m[6]*m[15]  - m[1]*m[7]*m[14]  - m[5]*m[2]*m[15] + m[5]*m[3]*m[14] + m[13]*m[2]*m[7]  - m[13]*m[3]*m[6];
    inv[6]  = -m[0]*m[6]*m[15]  + m[0]*m[7]*m[14]  + m[4]*m[2]*m[15] - m[4]*m[3]*m[14] - m[12]*m[2]*m[7]  + m[12]*m[3]*m[6];
    inv[10] =  m[0]*m[5]*m[15]  - m[0]*m[7]*m[13]  - m[4]*m[1]*m[15] + m[4]*m[3]*m[13] + m[12]*m[1]*m[7]  - m[12]*m[3]*m[5];
    inv[14] = -m[0]*m[5]*m[14]  + m[0]*m[6]*m[13]  + m[4]*m[1]*m[14] - m[4]*m[2]*m[13] - m[12]*m[1]*m[6]  + m[12]*m[2]*m[5];
    inv[3]  = -m[1]*m[6]*m[11]  + m[1]*m[7]*m[10]  + m[5]*m[2]*m[11] - m[5]*m[3]*m[10] - m[9]*m[2]*m[7]   + m[9]*m[3]*m[6];
    inv[7]  =  m[0]*m[6]*m[11]  - m[0]*m[7]*m[10]  - m[4]*m[2]*m[11] + m[4]*m[3]*m[10] + m[8]*m[2]*m[7]   - m[8]*m[3]*m[6];
    inv[11] = -m[0]*m[5]*m[11]  + m[0]*m[7]*m[9]   + m[4]*m[1]*m[11] - m[4]*m[3]*m[9]  - m[8]*m[1]*m[7]   + m[8]*m[3]*m[5];
    inv[15] =  m[0]*m[5]*m[10]  - m[0]*m[6]*m[9]   - m[4]*m[1]*m[10] + m[4]*m[2]*m[9]  + m[8]*m[1]*m[6]   - m[8]*m[2]*m[5];
    float det = m[0]*inv[0] + m[1]*inv[4] + m[2]*inv[8] + m[3]*inv[12];
    det = 1.0f / det;
    #pragma unroll
    for (int i = 0; i < 16; ++i) inv[i] *= det;
}

// ---------------------------------------------------------------------------
// Kernel 1: fused preprocess + stable bucket argsort + permute.
// Single block, 1024 threads. Output: evalps/bboxs in z-sorted order
// (stable (z, idx) — matches jnp.argsort). evalps slot .z of the 2nd float4
// holds the ORIGINAL gaussian index (for colors lookup).
__global__ __launch_bounds__(1024) void prep_sort_kernel(
    const float* __restrict__ means,  const float* __restrict__ quats,
    const float* __restrict__ scales, const float* __restrict__ opac_logits,
    const float* __restrict__ c2o,    const float* __restrict__ Kmat,
    float* __restrict__ evalp, float* __restrict__ bboxp,
    float* __restrict__ evalps, float* __restrict__ bboxs)
{
    __shared__ float zin[NG];
    __shared__ int   hist[NB];
    __shared__ int   startb[NB];
    __shared__ int   scanbuf[NB];
    __shared__ int   cursor[NB];
    __shared__ float zout[NG];
    __shared__ int   iout[NG];
    __shared__ float wmn[16], wmx[16];

    const int tid = threadIdx.x;

    float inv[16];
    {
        float m[16];
        #pragma unroll
        for (int t = 0; t < 16; ++t) m[t] = c2o[t];
        invert4x4(m, inv);   // viewmat, row-major
    }
    const float fx = Kmat[0], fy = Kmat[4], cx = Kmat[2], cy = Kmat[5];

    for (int i = tid; i < NB; i += 1024) hist[i] = 0;

    // ---- preprocess (2 gaussians per thread)
    for (int i = tid; i < NG; i += 1024) {
        float mx = means[i*3+0], my = means[i*3+1], mz = means[i*3+2];
        float X = inv[0]*mx + inv[1]*my + inv[2]*mz  + inv[3];
        float Y = inv[4]*mx + inv[5]*my + inv[6]*mz  + inv[7];
        float Z = inv[8]*mx + inv[9]*my + inv[10]*mz + inv[11];

        float qw = quats[i*4+0], qx = quats[i*4+1], qy = quats[i*4+2], qz = quats[i*4+3];
        float qn = rsqrtf(qw*qw + qx*qx + qy*qy + qz*qz);
        qw *= qn; qx *= qn; qy *= qn; qz *= qn;
        float R00 = 1.f - 2.f*(qy*qy + qz*qz), R01 = 2.f*(qx*qy - qw*qz), R02 = 2.f*(qx*qz + qw*qy);
        float R10 = 2.f*(qx*qy + qw*qz), R11 = 1.f - 2.f*(qx*qx + qz*qz), R12 = 2.f*(qy*qz - qw*qx);
        float R20 = 2.f*(qx*qz - qw*qy), R21 = 2.f*(qy*qz + qw*qx), R22 = 1.f - 2.f*(qx*qx + qy*qy);

        float s0 = expf(scales[i*3+0]), s1 = expf(scales[i*3+1]), s2 = expf(scales[i*3+2]);
        float M00 = R00*s0, M01 = R01*s1, M02 = R02*s2;
        float M10 = R10*s0, M11 = R11*s1, M12 = R12*s2;
        float M20 = R20*s0, M21 = R21*s1, M22 = R22*s2;

        float V[3][3];
        V[0][0] = M00*M00 + M01*M01 + M02*M02;
        V[0][1] = M00*M10 + M01*M11 + M02*M12;
        V[0][2] = M00*M20 + M01*M21 + M02*M22;
        V[1][1] = M10*M10 + M11*M11 + M12*M12;
        V[1][2] = M10*M20 + M11*M21 + M12*M22;
        V[2][2] = M20*M20 + M21*M21 + M22*M22;
        V[1][0] = V[0][1]; V[2][0] = V[0][2]; V[2][1] = V[1][2];

        float Rv[3][3] = {{inv[0],inv[1],inv[2]},{inv[4],inv[5],inv[6]},{inv[8],inv[9],inv[10]}};
        float Tm[3][3], C[3][3];
        #pragma unroll
        for (int r = 0; r < 3; ++r)
            #pragma unroll
            for (int c = 0; c < 3; ++c)
                Tm[r][c] = Rv[r][0]*V[0][c] + Rv[r][1]*V[1][c] + Rv[r][2]*V[2][c];
        #pragma unroll
        for (int r = 0; r < 3; ++r)
            #pragma unroll
            for (int c = 0; c < 3; ++c)
                C[r][c] = Tm[r][0]*Rv[c][0] + Tm[r][1]*Rv[c][1] + Tm[r][2]*Rv[c][2];

        float rz = 1.0f / Z;
        float j00 = fx*rz, j02 = -fx*X*rz*rz;
        float j11 = fy*rz, j12 = -fy*Y*rz*rz;

        float c00 = j00*j00*C[0][0] + 2.f*j00*j02*C[0][2] + j02*j02*C[2][2];
        float c01 = j00*j11*C[0][1] + j00*j12*C[0][2] + j02*j11*C[1][2] + j02*j12*C[2][2];
        float c11 = j11*j11*C[1][1] + 2.f*j11*j12*C[1][2] + j12*j12*C[2][2];

        float a = c00 + P_BLUR;
        float b = c01;
        float c = c11 + P_BLUR;
        float det = a*c - b*b;

        float pmx = fx*X*rz + cx;
        float pmy = fy*Y*rz + cy;

        float lam = 0.5f*(a + c) + sqrtf(fmaxf(0.25f*(a - c)*(a - c) + b*b, 1e-12f));
        float radius = 3.0f * sqrtf(lam);
        bool valid = (Z > P_NEAR) && (det > 0.0f) && (radius > 3.0f);

        float op = 1.0f / (1.0f + expf(-opac_logits[i]));

        float cA = 0.f, cB = 0.f, cC = 0.f, rx = -1e9f, ry = -1e9f;
        if (valid) {
            float rdet = 1.0f / det;
            cA = c * rdet; cB = -b * rdet; cC = a * rdet;
            // conservative pixel extent: alpha>=A_MIN needs sigma<=ln(255*op);
            // min-over-dy sigma = dx^2/(2a)  =>  |dx| <= sqrt(2*a*smax).
            float smax = logf(255.0f * op);
            if (smax > 0.f) {
                rx = sqrtf(2.f * a * smax) * 1.0001f + 1e-3f;
                ry = sqrtf(2.f * c * smax) * 1.0001f + 1e-3f;
            }
        } else {
            op = 0.f;
        }

        evalp[i*8+0] = pmx; evalp[i*8+1] = pmy;
        evalp[i*8+2] = cA;  evalp[i*8+3] = cB;
        evalp[i*8+4] = cC;  evalp[i*8+5] = op;
        evalp[i*8+6] = 0.f; evalp[i*8+7] = 0.f;
        bboxp[i*4+0] = pmx; bboxp[i*4+1] = pmy;
        bboxp[i*4+2] = rx;  bboxp[i*4+3] = ry;
        zin[i] = Z;
    }
    __syncthreads();

    // ---- min/max of z
    float mn = 1e30f, mx = -1e30f;
    for (int i = tid; i < NG; i += 1024) { float z = zin[i]; mn = fminf(mn, z); mx = fmaxf(mx, z); }
    #pragma unroll
    for (int off = 32; off; off >>= 1) { mn = fminf(mn, __shfl_down(mn, off)); mx = fmaxf(mx, __shfl_down(mx, off)); }
    if ((tid & 63) == 0) { wmn[tid >> 6] = mn; wmx[tid >> 6] = mx; }
    __syncthreads();
    if (tid == 0) {
        float a = wmn[0], b = wmx[0];
        for (int i = 1; i < 16; ++i) { a = fminf(a, wmn[i]); b = fmaxf(b, wmx[i]); }
        wmn[0] = a; wmx[0] = b;
    }
    __syncthreads();
    const float zmin = wmn[0], zmax = wmx[0];
    const float binv = (zmax > zmin) ? ((float)NB / (zmax - zmin)) * 0.999999f : 0.f;

    // ---- histogram
    for (int i = tid; i < NG; i += 1024) {
        int b = min((int)((zin[i] - zmin) * binv), NB - 1);
        atomicAdd(&hist[b], 1);
    }
    __syncthreads();

    // ---- inclusive scan (Hillis-Steele) -> exclusive start
    int v = hist[tid];
    scanbuf[tid] = v;
    __syncthreads();
    for (int off = 1; off < NB; off <<= 1) {
        int t = (tid >= off) ? scanbuf[tid - off] : 0;
        __syncthreads();
        scanbuf[tid] += t;
        __syncthreads();
    }
    startb[tid] = scanbuf[tid] - v;
    cursor[tid] = 0;
    __syncthreads();

    // ---- scatter (bucket-grouped, intra-bucket order arbitrary)
    for (int i = tid; i < NG; i += 1024) {
        float z = zin[i];
        int b = min((int)((z - zmin) * binv), NB - 1);
        int pos = startb[b] + atomicAdd(&cursor[b], 1);
        zout[pos] = z; iout[pos] = i;
    }
    __syncthreads();

    // ---- per-bucket insertion sort by (z, idx): exact stable order
    {
        int b = tid;
        int s = startb[b], e = s + hist[b];
        for (int i = s + 1; i < e; ++i) {
            float z = zout[i]; int id = iout[i];
            int j = i - 1;
            while (j >= s && (zout[j] > z || (zout[j] == z && iout[j] > id))) {
                zout[j+1] = zout[j]; iout[j+1] = iout[j]; --j;
            }
            zout[j+1] = z; iout[j+1] = id;
        }
    }
    __syncthreads();

    // ---- permute params into sorted order; stash original idx in e1.z
    const float4* ev4 = (const float4*)evalp;
    const float4* bb4 = (const float4*)bboxp;
    for (int i = tid; i < NG; i += 1024) {
        int j = iout[i];
        float4 a  = ev4[j*2];
        float4 b4 = ev4[j*2+1];
        b4.z = __int_as_float(j);
        ((float4*)evalps)[i*2]   = a;
        ((float4*)evalps)[i*2+1] = b4;
        ((float4*)bboxs)[i] = bb4[j];
    }
}

// ---------------------------------------------------------------------------
// Kernel 2: render. 256 blocks (one 8x8 tile each), 8 waves/block.
// Wave s owns z-segment s; lane = pixel. Serial front-to-back compositing in
// registers, colors streamed as wave-uniform broadcast float4 loads (no big
// register arrays -> no spill). Segments combined affinely in LDS epilogue.
__global__ __launch_bounds__(RB, 2) void render_kernel(
    const float* __restrict__ evalps, const float* __restrict__ bboxs,
    const float* __restrict__ colors, float* __restrict__ out)
{
    extern __shared__ float lds[];
    const int tid  = threadIdx.x;
    const int lane = tid & 63;
    const int seg  = tid >> 6;
    const int tile = blockIdx.x;
    const int tx = (tile & 15) * 8;
    const int ty = (tile >> 4) * 8;
    const float px = tx + (lane & 7) + 0.5f;
    const float py = ty + (lane >> 3) + 0.5f;
    const float cxt = tx + 4.0f, cyt = ty + 4.0f;

    // ---- cull this segment into an LDS list (z order preserved)
    int* list = (int*)(lds + L_LIST) + seg * SEGN;
    int cnt = 0;
    const float4* bb4 = (const float4*)bboxs;
    for (int c = 0; c < SEGN; c += 64) {
        int g = seg * SEGN + c + lane;           // sorted position
        float4 bb = bb4[g];
        bool sel = (fabsf(bb.x - cxt) <= bb.z + 3.5f) &&
                   (fabsf(bb.y - cyt) <= bb.w + 3.5f);
        unsigned long long m = __ballot(sel);
        if (sel) list[cnt + (int)__popcll(m & ((1ull << lane) - 1ull))] = g;
        cnt += (int)__popcll(m);
    }

    float acc[64];
    #pragma unroll
    for (int f = 0; f < 64; ++f) acc[f] = 0.f;
    float T = 1.0f;

    const float4* ep4 = (const float4*)evalps;
    const float4* cp4 = (const float4*)colors;

    if (cnt > 0) {
        int gi = list[0];
        float4 e0 = ep4[gi*2], e1 = ep4[gi*2+1];
        for (int r = 0; r < cnt; ++r) {
            int gin = (r + 1 < cnt) ? list[r + 1] : gi;
            float4 n0 = ep4[gin*2], n1 = ep4[gin*2+1];   // prefetch next params

            float dx = px - e0.x, dy = py - e0.y;
            float sig = 0.5f*(e0.z*dx*dx + e1.x*dy*dy) + e0.w*dx*dy;
            float al = fminf(e1.y * __expf(-sig), P_AMAX);
            al = (sig >= 0.f && al >= P_AMIN) ? al : 0.f;

            if (__ballot(al > 0.f)) {
                float wv = T * al;
                const float4* crow = cp4 + (size_t)(unsigned)__float_as_int(e1.z) * 16;
                #pragma unroll
                for (int q = 0; q < 16; ++q) {
                    float4 cv = crow[q];                  // wave-uniform broadcast
                    acc[4*q+0] = fmaf(wv, cv.x, acc[4*q+0]);
                    acc[4*q+1] = fmaf(wv, cv.y, acc[4*q+1]);
                    acc[4*q+2] = fmaf(wv, cv.z, acc[4*q+2]);
                    acc[4*q+3] = fmaf(wv, cv.w, acc[4*q+3]);
                }
                T *= (1.f - al);
                if (!__ballot(T >= 1e-6f)) break;   // whole wave dead -> done
            }
            e0 = n0; e1 = n1;
        }
    }

    // ---- stage per-segment (acc, T) to LDS
    {
        float* ab = lds + L_ACC + (size_t)(seg * 64 + lane) * ACC_STRIDE;
        #pragma unroll
        for (int q = 0; q < 32; ++q)
            *(float2*)(ab + 2*q) = make_float2(acc[2*q], acc[2*q+1]);
        lds[L_T + seg*64 + lane] = T;
    }
    __syncthreads();

    // ---- affine combine: out = a0 + T0*(a1 + T1*(...))
    {
        int p  = tid >> 3;
        int f0 = (tid & 7) * 8;
        float r[8];
        const float* ab = lds + L_ACC + (size_t)((SEG-1)*64 + p) * ACC_STRIDE + f0;
        #pragma unroll
        for (int j = 0; j < 4; ++j) {
            float2 u = *(const float2*)(ab + 2*j);
            r[2*j] = u.x; r[2*j+1] = u.y;
        }
        #pragma unroll
        for (int s = SEG - 2; s >= 0; --s) {
            float Ts = lds[L_T + s*64 + p];
            const float* as_ = lds + L_ACC + (size_t)(s*64 + p) * ACC_STRIDE + f0;
            #pragma unroll
            for (int j = 0; j < 4; ++j) {
                float2 u = *(const float2*)(as_ + 2*j);
                r[2*j]   = fmaf(Ts, r[2*j],   u.x);
                r[2*j+1] = fmaf(Ts, r[2*j+1], u.y);
            }
        }
        int pyg = ty + (p >> 3), pxg = tx + (p & 7);
        float* op_ = out + (size_t)(pyg * IW + pxg) * DF + f0;
        *(float4*)op_       = make_float4(r[0], r[1], r[2], r[3]);
        *(float4*)(op_ + 4) = make_float4(r[4], r[5], r[6], r[7]);
    }
}

// ---------------------------------------------------------------------------
extern "C" void kernel_launch(void* const* d_in, const int* in_sizes, int n_in,
                              void* d_out, int out_size, void* d_ws, size_t ws_size,
                              hipStream_t stream) {
    const float* means  = (const float*)d_in[0];
    const float* quats  = (const float*)d_in[1];
    const float* scales = (const float*)d_in[2];
    const float* opac   = (const float*)d_in[3];
    const float* colors = (const float*)d_in[4];
    const float* c2o    = (const float*)d_in[5];
    const float* Kmat   = (const float*)d_in[6];
    float* out = (float*)d_out;

    // ws (floats): evalp[NG*8] | bboxp[NG*4] | evalps[NG*8] | bboxs[NG*4] = 192 KiB
    float* ws     = (float*)d_ws;
    float* evalp  = ws;
    float* bboxp  = ws + NG*8;
    float* evalps = ws + NG*12;
    float* bboxs  = ws + NG*20;

    (void)hipFuncSetAttribute((const void*)render_kernel,
                              hipFuncAttributeMaxDynamicSharedMemorySize,
                              L_TOTAL * 4);

    prep_sort_kernel<<<1, 1024, 0, stream>>>(means, quats, scales, opac, c2o, Kmat,
                                             evalp, bboxp, evalps, bboxs);
    render_kernel<<<IH*IW/64, RB, L_TOTAL*4, stream>>>(evalps, bboxs, colors, out);
}